// Round 9
// baseline (302.822 us; speedup 1.0000x reference)
//
#include <hip/hip_runtime.h>
#include <cfloat>

#define NTOK (64 * 4096)   // 262144 tokens
#define HID  128
#define NE   64
#define TK   6
#define TS   7             // sort depth: top-7 needed for the safety gap test
#define BLK  512           // 8 waves/block: dispatch-slot carries 2x the waves
#define TPB  512           // tokens per block
#define GRID (NTOK / TPB)  // 512 blocks
// Packed sort keys (R7-proven): key = (int(logit*2^17) << 6) | (63 - e).
#define KSCALE 131072.0f
#define KINV   (1.0f / 131072.0f)
#define KTHR   1664        // ~2e-4 in key units; MFMA+quant err ~6e-5 << KTHR/2

typedef __attribute__((ext_vector_type(8))) short short8;  // 8 bf16 (4 VGPRs)
typedef __attribute__((ext_vector_type(4))) float f32x4;   // MFMA C/D

union UB { uint4 u; short8 s; };
__device__ __forceinline__ short8 u2s(const uint4 u) { UB x; x.u = u; return x.s; }
__device__ __forceinline__ int imax(int a, int b) { return a > b ? a : b; }
__device__ __forceinline__ int imin(int a, int b) { return a < b ? a : b; }

// 2-term round-to-nearest split: a ~= a1 + a2, |a - a1 - a2| <= 2^-18 |a|.
__device__ __forceinline__ void split2(float a, float b, unsigned& d1, unsigned& d2) {
    unsigned p1;
    asm("v_cvt_pk_bf16_f32 %0, %1, %2" : "=v"(p1) : "v"(a), "v"(b));
    const float a1 = __uint_as_float(p1 << 16);
    const float b1 = __uint_as_float(p1 & 0xFFFF0000u);
    const float ra = a - a1;
    const float rb = b - b1;
    unsigned p2;
    asm("v_cvt_pk_bf16_f32 %0, %1, %2" : "=v"(p2) : "v"(ra), "v"(rb));
    d1 = p1; d2 = p2;
}

__device__ __forceinline__ void split8(const float4 v0, const float4 v1,
                                       uint4& o1, uint4& o2) {
    split2(v0.x, v0.y, o1.x, o2.x);
    split2(v0.z, v0.w, o1.y, o2.y);
    split2(v1.x, v1.y, o1.z, o2.z);
    split2(v1.z, v1.w, o1.w, o2.w);
}

// R9: R7-proven kernel widened to 8 waves/block (occupancy-per-dispatch-slot
// hypothesis: resident waves ~ dispatch_rate x block_lifetime x waves/block;
// 17% occupancy was invariant to LDS/VGPR across R2-R8 but rose to 42% for
// long-lived blocks in R1). + aux fused into last block (one launch removed).
__global__ __launch_bounds__(BLK)
void gate_kernel(const float* __restrict__ X,
                 const float* __restrict__ W,
                 float* __restrict__ oidx,
                 float* __restrict__ ow,
                 float* __restrict__ Pi_g,
                 unsigned int* __restrict__ cnt_g,
                 unsigned int* __restrict__ done_g,
                 float* __restrict__ aux_out)
{
    __shared__ uint4        Wlds[2 * 1024];   // 32 KB: RNE-split W frags
    __shared__ float        Pi_s[8][NE];
    __shared__ unsigned int cnt_s[NE];
    __shared__ unsigned int flags_s[TPB];     // flagged token-local ids
    __shared__ unsigned int nflag_s;
    __shared__ unsigned int lastblk_s;

    const int tid  = threadIdx.x;
    const int lane = tid & 63;
    const int wv   = __builtin_amdgcn_readfirstlane(tid >> 6);  // 0..7
    const int col  = lane & 15;
    const int g    = lane >> 4;

    if (tid < NE) cnt_s[tid] = 0u;
    if (tid == 0) nflag_s = 0u;

    // ---- one-time: RNE-split W (64x128 f32) into 2 bf16 frag arrays
    {
        const float4* W4 = (const float4*)W;
#pragma unroll
        for (int i = 0; i < 2; ++i) {
            const int slot = tid + i * BLK;          // [0,1024) = fid*64 + ln
            const int fid  = slot >> 6;              // et*4 + kt
            const int ln   = slot & 63;
            const int e    = ((fid >> 2) << 4) + (ln & 15);
            const int kq   = ((fid & 3) << 3) + ((ln >> 4) << 1);
            const float4 v0 = W4[e * 32 + kq];
            const float4 v1 = W4[e * 32 + kq + 1];
            uint4 o1, o2;
            split8(v0, v1, o1, o2);
            Wlds[slot]        = o1;
            Wlds[1024 + slot] = o2;
        }
    }
    __syncthreads();

    const int tok0 = blockIdx.x * TPB + wv * 64;

    f32x4 acc[4][4];   // [tt][et]
#pragma unroll
    for (int tt = 0; tt < 4; ++tt)
#pragma unroll
        for (int et = 0; et < 4; ++et) acc[tt][et] = (f32x4)0.0f;

    // ---- GEMM (R5-R8 proven): 4 kt x {X-splits, 4 et x 4 products}
#pragma unroll
    for (int kt = 0; kt < 4; ++kt) {
        uint4 xs[2][4];   // [split][tt]
#pragma unroll
        for (int tt = 0; tt < 4; ++tt) {
            const float4* xp = (const float4*)(X + (size_t)(tok0 + tt * 16 + col) * HID)
                               + (kt * 8 + g * 2);
            split8(xp[0], xp[1], xs[0][tt], xs[1][tt]);
        }
#pragma unroll
        for (int et = 0; et < 4; ++et) {
            const int fb = ((et << 2) + kt) * 64 + lane;
            const short8 w1 = u2s(Wlds[fb]);
            const short8 w2 = u2s(Wlds[1024 + fb]);
#define MM4(WF, XI) { \
            acc[0][et] = __builtin_amdgcn_mfma_f32_16x16x32_bf16(WF, u2s(xs[XI][0]), acc[0][et], 0, 0, 0); \
            acc[1][et] = __builtin_amdgcn_mfma_f32_16x16x32_bf16(WF, u2s(xs[XI][1]), acc[1][et], 0, 0, 0); \
            acc[2][et] = __builtin_amdgcn_mfma_f32_16x16x32_bf16(WF, u2s(xs[XI][2]), acc[2][et], 0, 0, 0); \
            acc[3][et] = __builtin_amdgcn_mfma_f32_16x16x32_bf16(WF, u2s(xs[XI][3]), acc[3][et], 0, 0, 0); }
            MM4(w1, 0) MM4(w1, 1) MM4(w2, 0) MM4(w2, 1)
#undef MM4
        }
    }

    // ---- epilogue (R7-proven): packed-key sort, registers + shuffles.
    // acc[tt][et][r] = logit(token = tok0+tt*16+col, expert = et*16+g*4+r)
    float pi[16];
#pragma unroll
    for (int j = 0; j < 16; ++j) pi[j] = 0.0f;

#pragma unroll
    for (int tt = 0; tt < 4; ++tt) {
        int tv[TS];
#pragma unroll
        for (int q = 0; q < TS; ++q) tv[q] = (int)0x80000000;
#pragma unroll
        for (int j = 0; j < 16; ++j) {
            const float f = acc[tt][j >> 2][j & 3];
            const int  ik = (int)(f * KSCALE);
            const int   e = ((j >> 2) << 4) + (g << 2) + (j & 3);
            int m = (int)(((unsigned)ik << 6) | (unsigned)(63 - e));
#pragma unroll
            for (int q = 0; q < TS; ++q) {
                const int t = tv[q];
                tv[q] = imax(t, m);
                m     = imin(t, m);
            }
        }
        const float ml = (float)(tv[0] >> 6) * KINV;   // quantized lane max
        float Zl = 0.0f;
#pragma unroll
        for (int j = 0; j < 16; ++j) {
            const float e = __expf(acc[tt][j >> 2][j & 3] - ml);
            acc[tt][j >> 2][j & 3] = e;                // keep exp for Pi pass
            Zl += e;
        }
        // merge the 4 lane-groups' sorted 7-lists: levels xor 16, 32
        float m_self = ml, Z = Zl;
#pragma unroll
        for (int lv = 16; lv <= 32; lv <<= 1) {
            int rv[TS];
#pragma unroll
            for (int q = 0; q < TS; ++q) rv[q] = __shfl_xor(tv[q], lv);
            const float m_p = (float)(rv[0] >> 6) * KINV;
            const float Z_p = __shfl_xor(Z, lv);
#pragma unroll
            for (int q2 = 0; q2 < TS; ++q2) {
                int m = rv[q2];
#pragma unroll
                for (int q = 0; q < TS; ++q) {
                    const int t = tv[q];
                    tv[q] = imax(t, m);
                    m     = imin(t, m);
                }
            }
            const float m_n = (float)(tv[0] >> 6) * KINV;
            Z = Z * __expf(m_self - m_n) + Z_p * __expf(m_p - m_n);
            m_self = m_n;
        }
        const float mx  = (float)(tv[0] >> 6) * KINV;  // quantized global max
        const float rzt = 1.0f / Z;
        float ex[TK]; float s = 0.0f;
#pragma unroll
        for (int q = 0; q < TK; ++q) {
            ex[q] = __expf((float)(tv[q] >> 6) * KINV - mx);
            s += ex[q];
        }
        const float rs = 1.0f / (s + 1e-20f);
        if (g == tt) {                          // writer lane: token = tok0 + lane
            bool flag = false;
#pragma unroll
            for (int q = 0; q < TK; ++q) flag |= (tv[q] - tv[q + 1]) < KTHR;
            int te[TK];
#pragma unroll
            for (int q = 0; q < TK; ++q) te[q] = 63 - (tv[q] & 63);
            const size_t gt = (size_t)(tok0 + lane) * TK;
            float2* ip = (float2*)(oidx + gt);
            float2* wp = (float2*)(ow + gt);
            ip[0] = make_float2((float)te[0], (float)te[1]);
            ip[1] = make_float2((float)te[2], (float)te[3]);
            ip[2] = make_float2((float)te[4], (float)te[5]);
            wp[0] = make_float2(ex[0] * rs, ex[1] * rs);
            wp[1] = make_float2(ex[2] * rs, ex[3] * rs);
            wp[2] = make_float2(ex[4] * rs, ex[5] * rs);
            if (!flag) {
#pragma unroll
                for (int q = 0; q < TK; ++q) atomicAdd(&cnt_s[te[q]], 1u);
            } else {
                const unsigned slot = atomicAdd(&nflag_s, 1u);
                flags_s[slot] = (unsigned)(wv * 64 + lane);
            }
        }
        const float sc = __expf(ml - mx) * rzt;
#pragma unroll
        for (int j = 0; j < 16; ++j)
            pi[j] = fmaf(acc[tt][j >> 2][j & 3], sc, pi[j]);
    }

    // Pi reduce across the 16 col-lanes sharing this lane's expert set
#pragma unroll
    for (int sh = 1; sh <= 8; sh <<= 1)
#pragma unroll
        for (int j = 0; j < 16; ++j) pi[j] += __shfl_xor(pi[j], sh);
    if (col == 0) {
#pragma unroll
        for (int j = 0; j < 16; ++j)
            Pi_s[wv][((j >> 2) << 4) + (g << 2) + (j & 3)] = pi[j];
    }
    __syncthreads();

    // ---- rescue: fp32 rescore flagged tokens, bit-identical to round-0 math.
    {
        const int nf = (int)nflag_s;            // uniform after barrier
        for (int i = wv; i < nf; i += 8) {
            const int tl = (int)flags_s[i];
            const float4* xr = (const float4*)(X + (size_t)(blockIdx.x * TPB + tl) * HID);
            const float4* wr = (const float4*)(W + (size_t)lane * HID);
            float a = 0.0f;
#pragma unroll 8
            for (int kq = 0; kq < 32; ++kq) {   // k strictly ascending 0..127
                const float4 xv = xr[kq];
                const float4 wv4 = wr[kq];
                a = fmaf(xv.x, wv4.x, a);
                a = fmaf(xv.y, wv4.y, a);
                a = fmaf(xv.z, wv4.z, a);
                a = fmaf(xv.w, wv4.w, a);
            }
            float tv[TK]; int ti[TK];
#pragma unroll
            for (int q = 0; q < TK; ++q) { tv[q] = -FLT_MAX; ti[q] = 0; }
            for (int e = 0; e < NE; ++e) {      // ascending e: stable tie order
                float m = __shfl(a, e);
                int  mi = e;
#pragma unroll
                for (int q = 0; q < TK; ++q) {
                    const bool  cx = m > tv[q];
                    const float nt = cx ? m     : tv[q];
                    const float nm = cx ? tv[q] : m;
                    const int   ni = cx ? mi    : ti[q];
                    const int   nj = cx ? ti[q] : mi;
                    tv[q] = nt; m = nm; ti[q] = ni; mi = nj;
                }
            }
            const float mx = tv[0];
            float ex[TK]; float s = 0.0f;
#pragma unroll
            for (int q = 0; q < TK; ++q) { ex[q] = __expf(tv[q] - mx); s += ex[q]; }
            const float rs = 1.0f / (s + 1e-20f);
            if (lane == 0) {
                const size_t gt = (size_t)(blockIdx.x * TPB + tl) * TK;
                float2* ip = (float2*)(oidx + gt);
                float2* wp = (float2*)(ow + gt);
                ip[0] = make_float2((float)ti[0], (float)ti[1]);
                ip[1] = make_float2((float)ti[2], (float)ti[3]);
                ip[2] = make_float2((float)ti[4], (float)ti[5]);
                wp[0] = make_float2(ex[0] * rs, ex[1] * rs);
                wp[1] = make_float2(ex[2] * rs, ex[3] * rs);
                wp[2] = make_float2(ex[4] * rs, ex[5] * rs);
#pragma unroll
                for (int q = 0; q < TK; ++q) atomicAdd(&cnt_s[ti[q]], 1u);
            }
        }
    }
    __syncthreads();

    if (tid < NE) {
        atomicAdd(&Pi_g[tid], Pi_s[0][tid] + Pi_s[1][tid] + Pi_s[2][tid] + Pi_s[3][tid]
                            + Pi_s[4][tid] + Pi_s[5][tid] + Pi_s[6][tid] + Pi_s[7][tid]);
        atomicAdd(&cnt_g[tid], cnt_s[tid]);
    }

    // ---- aux fold: last finished block computes the scalar (saves a launch).
    // __syncthreads drains vmcnt -> this block's atomics are complete before
    // the done-increment; done==GRID-1 implies all other blocks' adds are at
    // the coherent point; atomic-RMW reads below see them (device scope).
    __syncthreads();
    __threadfence();
    if (tid == 0)
        lastblk_s = (atomicAdd(done_g, 1u) == (unsigned)(GRID - 1)) ? 1u : 0u;
    __syncthreads();
    if (lastblk_s && tid < NE) {               // tid<64 == wave 0
        const float Pi = atomicAdd(&Pi_g[tid], 0.0f) * (1.0f / (float)NTOK);
        const float ce = (float)atomicAdd(&cnt_g[tid], 0u) * (1.0f / (float)(NTOK * TK));
        float v = Pi * ce * (float)NE;
#pragma unroll
        for (int off = 32; off > 0; off >>= 1) v += __shfl_down(v, off);
        if (tid == 0) aux_out[0] = v * 1.0e-3f;
    }
}

extern "C" void kernel_launch(void* const* d_in, const int* in_sizes, int n_in,
                              void* d_out, int out_size, void* d_ws, size_t ws_size,
                              hipStream_t stream) {
    const float* X = (const float*)d_in[0];
    const float* W = (const float*)d_in[1];

    float* out  = (float*)d_out;
    float* oidx = out;                          // N*6 indices (as float)
    float* ow   = out + (size_t)NTOK * TK;      // N*6 weights
    float* aux  = out + (size_t)NTOK * TK * 2;  // 1 scalar

    float*        Pi_g   = (float*)d_ws;
    unsigned int* cnt_g  = (unsigned int*)((char*)d_ws + 256);
    unsigned int* done_g = (unsigned int*)((char*)d_ws + 512);

    hipMemsetAsync(d_ws, 0, 768, stream);
    gate_kernel<<<GRID, BLK, 0, stream>>>(X, W, oidx, ow, Pi_g, cnt_g, done_g, aux);
}